// Round 5
// baseline (374.756 us; speedup 1.0000x reference)
//
#include <hip/hip_runtime.h>

#define IMG_H 512
#define IMG_W 512
#define NIMG 96            // B*C
#define WOUT 506
#define STRIP 11
#define NSTRIPS 46         // 46*11 = 506
#define NBLK (NSTRIPS*NIMG)   // 4416, divisible by 8
#define TOTAL_VALS 24579456.0f   // 96 * 506 * 506
#define MM_CHUNKS 16       // minmax partials per image

// ws layout (floats): pmn[1536] @0, pmx[1536] @8192, pss[NBLK] @16384
#define WS_MN 0
#define WS_MX 8192
#define WS_SS 16384
#define WS_NEED ((WS_SS + NBLK) * 4)

__device__ __forceinline__ int swz(int bid){           // XCD-bijective (NBLK%8==0)
    return (bid & 7) * (NBLK / 8) + (bid >> 3);
}

// ---------------- kernel 1: per-(img,chunk) min/max partials of img2 -------
// 1536 blocks x 256 thr = 6 waves/SIMD -> BW-bound; also warms L3 with img2.
__global__ __launch_bounds__(256) void minmax_part(const float* __restrict__ img2,
                                                   float* __restrict__ ws){
    __shared__ float s_mn[4], s_mx[4];
    int blk  = blockIdx.x;          // 0..1535
    int img  = blk >> 4;
    int chnk = blk & 15;
    const float4* base = (const float4*)(img2 + (size_t)img * (IMG_H*IMG_W)) + chnk * 4096;
    float mn = 3.4e38f, mx = -3.4e38f;
    #pragma unroll 4
    for (int i = threadIdx.x; i < 4096; i += 256){
        float4 v = base[i];
        mn = fminf(mn, fminf(fminf(v.x, v.y), fminf(v.z, v.w)));
        mx = fmaxf(mx, fmaxf(fmaxf(v.x, v.y), fmaxf(v.z, v.w)));
    }
    #pragma unroll
    for (int off = 32; off; off >>= 1){
        mn = fminf(mn, __shfl_down(mn, off));
        mx = fmaxf(mx, __shfl_down(mx, off));
    }
    int wave = threadIdx.x >> 6;
    if ((threadIdx.x & 63) == 0){ s_mn[wave] = mn; s_mx[wave] = mx; }
    __syncthreads();
    if (threadIdx.x == 0){
        mn = fminf(fminf(s_mn[0], s_mn[1]), fminf(s_mn[2], s_mn[3]));
        mx = fmaxf(fmaxf(s_mx[0], s_mx[1]), fmaxf(s_mx[2], s_mx[3]));
        ws[WS_MN + blk] = mn;
        ws[WS_MX + blk] = mx;
    }
}

// ---------------- kernel 2: SSIM map + per-block partial ----------------
// One wave per block, thread t owns input columns [8t, 8t+8).
// Vertical 7-row sliding sums in registers. Horizontal 7-window computed
// incrementally (5 running sums, 6 neighbor shuffles per quantity).
// Entering row prefetched ONE FULL ITERATION ahead (covers HBM latency);
// leaving row (touched 7 rows ago, L2-resident) loaded same-iteration.

#define ROWOP(row, OPA) { \
    const float* xr = x + (size_t)(row)*IMG_W + c0; \
    const float* yr = y + (size_t)(row)*IMG_W + c0; \
    float4 xa = *(const float4*)xr;     float4 xb = *(const float4*)(xr+4); \
    float4 ya = *(const float4*)yr;     float4 yb = *(const float4*)(yr+4); \
    float xv[8] = {xa.x,xa.y,xa.z,xa.w,xb.x,xb.y,xb.z,xb.w}; \
    float yv[8] = {ya.x,ya.y,ya.z,ya.w,yb.x,yb.y,yb.z,yb.w}; \
    _Pragma("unroll") \
    for (int k = 0; k < 8; k++){ \
        sx[k]  OPA xv[k]; \
        sy[k]  OPA yv[k]; \
        sxx[k] OPA xv[k]*xv[k]; \
        syy[k] OPA yv[k]*yv[k]; \
        sxy[k] OPA xv[k]*yv[k]; \
    } }

#define SSIMJ(j) { \
    if (c0 + (j) < WOUT){ \
        float P_ = wx, Q_ = wy; \
        float t1_ = P_*Q_; \
        float t2_ = fmaf(P_, P_, Q_*Q_); \
        float a1_ = fmaf(2.0f, t1_, c1s); \
        float b1_ = t2_ + c1s; \
        float u_  = fmaf(49.0f, wxy, -t1_); \
        float a2_ = fmaf(CO2, u_, c2s); \
        float v_  = fmaf(49.0f, wxx+wyy, -t2_); \
        float b2_ = fmaf(COV, v_, c2s); \
        accS += (a1_*a2_) * __builtin_amdgcn_rcpf(b1_*b2_); \
    } }

#define WADV(ax,bx, ay,by, axx,bxx, ayy,byy, axy,bxy) \
    wx  += (ax)  - (bx);   wy  += (ay)  - (by); \
    wxx += (axx) - (bxx);  wyy += (ayy) - (byy);  wxy += (axy) - (bxy);

template<int USE_WS>
__global__ __launch_bounds__(64, 4) void ssim_kernel(const float* __restrict__ img1,
                                                     const float* __restrict__ img2,
                                                     float* __restrict__ ws,
                                                     float* __restrict__ acc){
    int L     = swz(blockIdx.x);
    int img   = L / NSTRIPS;
    int strip = L - img * NSTRIPS;
    int b     = img / 3;

    // data range of batch b: reduce 48 contiguous partials (uniform -> scalar)
    float mn = 3.4e38f, mx = -3.4e38f;
    if (USE_WS){
        const float* pmn = ws + WS_MN + b * 3 * MM_CHUNKS;
        const float* pmx = ws + WS_MX + b * 3 * MM_CHUNKS;
        #pragma unroll 8
        for (int i = 0; i < 3*MM_CHUNKS; i++){
            mn = fminf(mn, pmn[i]);
            mx = fmaxf(mx, pmx[i]);
        }
    } else {
        unsigned mk = ((const unsigned*)ws)[b];
        unsigned nk = ((const unsigned*)ws)[32 + b];
        unsigned mb = (mk & 0x80000000u) ? (mk ^ 0x80000000u) : ~mk;
        unsigned nb = (nk & 0x80000000u) ? (nk ^ 0x80000000u) : ~nk;
        mx = __uint_as_float(mb); mn = __uint_as_float(nb);
    }
    float dr = mx - mn;
    float c1 = 0.01f * dr;  c1 *= c1;
    float c2 = 0.03f * dr;  c2 *= c2;
    const float c1s = 2401.0f * c1;           // raw 7x7-sum domain (scale 49^2)
    const float c2s = 2401.0f * c2;
    const float CO2 = 2.0f * 49.0f / 48.0f;
    const float COV = 49.0f / 48.0f;

    const float* x = img1 + (size_t)img * (IMG_H*IMG_W);
    const float* y = img2 + (size_t)img * (IMG_H*IMG_W);

    int t  = threadIdx.x;
    int c0 = t * 8;
    int r0 = strip * STRIP;

    float sx[8]={0,0,0,0,0,0,0,0}, sy[8]={0,0,0,0,0,0,0,0};
    float sxx[8]={0,0,0,0,0,0,0,0}, syy[8]={0,0,0,0,0,0,0,0}, sxy[8]={0,0,0,0,0,0,0,0};

    #pragma unroll
    for (int rr = 0; rr < 7; rr++){ ROWOP(r0+rr, +=) }

    // depth-2 prefetch buffer: entering row r0+7+i for slide i
    float4 eX0, eX1, eY0, eY1;
    {
        const float* xe = x + (size_t)(r0+7)*IMG_W + c0;
        const float* ye = y + (size_t)(r0+7)*IMG_W + c0;
        eX0 = *(const float4*)xe;  eX1 = *(const float4*)(xe+4);
        eY0 = *(const float4*)ye;  eY1 = *(const float4*)(ye+4);
    }

    float accS = 0.0f;

    #pragma unroll
    for (int i = 0; i < STRIP; i++){
        // ---- issue next-iteration's entering row + this iteration's leaving row
        float4 nX0, nX1, nY0, nY1, lX0, lX1, lY0, lY1;
        if (i < STRIP-2){
            const float* xe = x + (size_t)(r0+8+i)*IMG_W + c0;
            const float* ye = y + (size_t)(r0+8+i)*IMG_W + c0;
            nX0 = *(const float4*)xe;  nX1 = *(const float4*)(xe+4);
            nY0 = *(const float4*)ye;  nY1 = *(const float4*)(ye+4);
        }
        if (i < STRIP-1){
            const float* xl = x + (size_t)(r0+i)*IMG_W + c0;
            const float* yl = y + (size_t)(r0+i)*IMG_W + c0;
            lX0 = *(const float4*)xl;  lX1 = *(const float4*)(xl+4);
            lY0 = *(const float4*)yl;  lY1 = *(const float4*)(yl+4);
        }

        // ---- neighbor column sums (6 per quantity, issued as a batch)
        float nx0=__shfl_down(sx[0],1),  nx1=__shfl_down(sx[1],1),  nx2=__shfl_down(sx[2],1),
              nx3=__shfl_down(sx[3],1),  nx4=__shfl_down(sx[4],1),  nx5=__shfl_down(sx[5],1);
        float ny0=__shfl_down(sy[0],1),  ny1=__shfl_down(sy[1],1),  ny2=__shfl_down(sy[2],1),
              ny3=__shfl_down(sy[3],1),  ny4=__shfl_down(sy[4],1),  ny5=__shfl_down(sy[5],1);
        float nxx0=__shfl_down(sxx[0],1), nxx1=__shfl_down(sxx[1],1), nxx2=__shfl_down(sxx[2],1),
              nxx3=__shfl_down(sxx[3],1), nxx4=__shfl_down(sxx[4],1), nxx5=__shfl_down(sxx[5],1);
        float nyy0=__shfl_down(syy[0],1), nyy1=__shfl_down(syy[1],1), nyy2=__shfl_down(syy[2],1),
              nyy3=__shfl_down(syy[3],1), nyy4=__shfl_down(syy[4],1), nyy5=__shfl_down(syy[5],1);
        float nxy0=__shfl_down(sxy[0],1), nxy1=__shfl_down(sxy[1],1), nxy2=__shfl_down(sxy[2],1),
              nxy3=__shfl_down(sxy[3],1), nxy4=__shfl_down(sxy[4],1), nxy5=__shfl_down(sxy[5],1);

        // ---- incremental horizontal 7-window + SSIM
        float wx  = sx[0]+sx[1]+sx[2]+sx[3]+sx[4]+sx[5]+sx[6];
        float wy  = sy[0]+sy[1]+sy[2]+sy[3]+sy[4]+sy[5]+sy[6];
        float wxx = sxx[0]+sxx[1]+sxx[2]+sxx[3]+sxx[4]+sxx[5]+sxx[6];
        float wyy = syy[0]+syy[1]+syy[2]+syy[3]+syy[4]+syy[5]+syy[6];
        float wxy = sxy[0]+sxy[1]+sxy[2]+sxy[3]+sxy[4]+sxy[5]+sxy[6];
        SSIMJ(0)
        WADV(sx[7],sx[0], sy[7],sy[0], sxx[7],sxx[0], syy[7],syy[0], sxy[7],sxy[0])  SSIMJ(1)
        WADV(nx0,sx[1],  ny0,sy[1],  nxx0,sxx[1],  nyy0,syy[1],  nxy0,sxy[1])        SSIMJ(2)
        WADV(nx1,sx[2],  ny1,sy[2],  nxx1,sxx[2],  nyy1,syy[2],  nxy1,sxy[2])        SSIMJ(3)
        WADV(nx2,sx[3],  ny2,sy[3],  nxx2,sxx[3],  nyy2,syy[3],  nxy2,sxy[3])        SSIMJ(4)
        WADV(nx3,sx[4],  ny3,sy[4],  nxx3,sxx[4],  nyy3,syy[4],  nxy3,sxy[4])        SSIMJ(5)
        WADV(nx4,sx[5],  ny4,sy[5],  nxx4,sxx[5],  nyy4,syy[5],  nxy4,sxy[5])        SSIMJ(6)
        WADV(nx5,sx[6],  ny5,sy[6],  nxx5,sxx[6],  nyy5,syy[6],  nxy5,sxy[6])        SSIMJ(7)

        // ---- apply slide i: enter row (prefetched last iter), leave row
        if (i < STRIP-1){
            float xv[8]  = {eX0.x,eX0.y,eX0.z,eX0.w, eX1.x,eX1.y,eX1.z,eX1.w};
            float yv[8]  = {eY0.x,eY0.y,eY0.z,eY0.w, eY1.x,eY1.y,eY1.z,eY1.w};
            float lxv[8] = {lX0.x,lX0.y,lX0.z,lX0.w, lX1.x,lX1.y,lX1.z,lX1.w};
            float lyv[8] = {lY0.x,lY0.y,lY0.z,lY0.w, lY1.x,lY1.y,lY1.z,lY1.w};
            #pragma unroll
            for (int k = 0; k < 8; k++){
                sx[k]  += xv[k] - lxv[k];
                sy[k]  += yv[k] - lyv[k];
                sxx[k] = fmaf(xv[k], xv[k], fmaf(-lxv[k], lxv[k], sxx[k]));
                syy[k] = fmaf(yv[k], yv[k], fmaf(-lyv[k], lyv[k], syy[k]));
                sxy[k] = fmaf(xv[k], yv[k], fmaf(-lxv[k], lyv[k], sxy[k]));
            }
        }
        if (i < STRIP-2){ eX0=nX0; eX1=nX1; eY0=nY0; eY1=nY1; }
    }

    #pragma unroll
    for (int off = 32; off; off >>= 1)
        accS += __shfl_down(accS, off);
    if (t == 0){
        if (USE_WS) ws[WS_SS + L] = accS;
        else        atomicAdd(acc, accS);
    }
}

// ---------------- kernel 3: reduce partials + finalize ----------------
__global__ __launch_bounds__(64) void finalize_ws(const float* __restrict__ ws,
                                                  float* __restrict__ out){
    float s = 0.0f;
    for (int i = threadIdx.x; i < NBLK; i += 64) s += ws[WS_SS + i];
    #pragma unroll
    for (int off = 32; off; off >>= 1) s += __shfl_down(s, off);
    if (threadIdx.x == 0) out[0] = 1.0f - s * (1.0f / TOTAL_VALS);
}

__global__ void finalize_acc(const float* __restrict__ acc, float* __restrict__ out){
    out[0] = 1.0f - acc[0] * (1.0f / TOTAL_VALS);
}

// ---------------- fallback minmax (atomic, needs memset init) ----------------
__device__ __forceinline__ unsigned fkey(float f){
    unsigned b = __float_as_uint(f);
    return (b & 0x80000000u) ? ~b : (b | 0x80000000u);
}
__global__ __launch_bounds__(256) void minmax_atomic(const float4* __restrict__ y4,
                                                     unsigned* __restrict__ ws){
    int blk  = blockIdx.x;
    int img  = blk >> 6;
    int chnk = blk & 63;
    const float4* base = y4 + (size_t)img * 196608 + (size_t)chnk * 3072;
    float mn = 3.4e38f, mx = -3.4e38f;
    for (int i = threadIdx.x; i < 3072; i += 256){
        float4 v = base[i];
        mn = fminf(mn, fminf(fminf(v.x, v.y), fminf(v.z, v.w)));
        mx = fmaxf(mx, fmaxf(fmaxf(v.x, v.y), fmaxf(v.z, v.w)));
    }
    #pragma unroll
    for (int off = 32; off; off >>= 1){
        mn = fminf(mn, __shfl_down(mn, off));
        mx = fmaxf(mx, __shfl_down(mx, off));
    }
    if ((threadIdx.x & 63) == 0){
        atomicMax(&ws[img], fkey(mx));
        atomicMin(&ws[32 + img], fkey(mn));
    }
}

extern "C" void kernel_launch(void* const* d_in, const int* in_sizes, int n_in,
                              void* d_out, int out_size, void* d_ws, size_t ws_size,
                              hipStream_t stream) {
    const float* img1 = (const float*)d_in[0];
    const float* img2 = (const float*)d_in[1];
    float* out = (float*)d_out;
    float* ws  = (float*)d_ws;

    if (ws_size >= WS_NEED){
        // atomic-free, memset-free 3-kernel pipeline
        minmax_part<<<NIMG*MM_CHUNKS, 256, 0, stream>>>(img2, ws);
        ssim_kernel<1><<<NBLK, 64, 0, stream>>>(img1, img2, ws, nullptr);
        finalize_ws<<<1, 64, 0, stream>>>(ws, out);
    } else {
        // fallback: small-ws atomic path
        hipMemsetAsync(ws, 0, 160, stream);                 // maxkeys + acc
        hipMemsetAsync((char*)ws + 128, 0xFF, 128, stream); // minkeys
        hipMemsetAsync((char*)ws + 256, 0, 16, stream);     // acc
        float* acc = ws + 64;
        minmax_atomic<<<2048, 256, 0, stream>>>((const float4*)img2, (unsigned*)ws);
        ssim_kernel<0><<<NBLK, 64, 0, stream>>>(img1, img2, ws, acc);
        finalize_acc<<<1, 1, 0, stream>>>(acc, out);
    }
}